// Round 3
// baseline (687.380 us; speedup 1.0000x reference)
//
#include <hip/hip_runtime.h>
#include <math.h>

#define N_NODES 100000
#define N_EDGES 3200000
#define BSHIFT 7
#define BNODES 128                         // nodes per bucket
#define NB 782                             // ceil(N_NODES/128)
#define PLACE_BLOCKS 400

// ---------------------------------------------------------------------------
// gemm1: h[N,16] = x[N,512] @ W1[512,16]
// R4: one-shot tile staging. R1/R3 post-mortem: all prior variants were
// request-concurrency-bound (stage->vmcnt(0)->barrier->compute keeps only
// 2-8 loads/thread in flight, 0 during compute -> 1.1-1.4 TB/s blended).
// Here each block stages its ENTIRE 32x512 tile (64KB) with 16 independent
// float4 loads/thread (16KB in flight per wave), ONE barrier, then computes
// all 512 k from LDS. 100000 = 32*3125 exactly -> no row guards.
// LDS 66KB -> 2 blocks/CU: one stages while the other computes.
// Compute mapping: rq=t>>3 (row), cg=(t>>1)&3 (col group), kh=t&1 (k half);
// k-half partials combined via 4 shfl_xor(.,1). Stride 516 -> read bank
// starts {0,4,..,28} per rq, kh aliases 2-way (free); staging writes are
// lane-contiguous b128 (canonical conflict-free).
// ---------------------------------------------------------------------------
__global__ __launch_bounds__(256) void gemm1_kernel(
    const float* __restrict__ x, const float* __restrict__ W1,
    float* __restrict__ h)
{
    __shared__ __align__(16) float xs[32 * 516];
    const int t = threadIdx.x;
    const int rbase = blockIdx.x * 32;

    // stage 32 rows x 512 k: 4096 float4, 16 per thread, all independent
    const float4* __restrict__ x4 = (const float4*)x;
    #pragma unroll
    for (int i = 0; i < 16; ++i) {
        int idx = i * 256 + t;          // 0..4095
        int row = idx >> 7;             // 0..31
        int c4  = idx & 127;            // float4 index within row
        float4 v = x4[(size_t)(rbase + row) * 128 + c4];
        *(float4*)(xs + row * 516 + c4 * 4) = v;
    }
    __syncthreads();

    const int rq = t >> 3;              // 0..31
    const int cg = (t >> 1) & 3;        // 0..3
    const int kh = t & 1;               // 0..1
    const float4* __restrict__ w4 = (const float4*)W1;   // w4[k*4+cg]
    const float* __restrict__ xr = xs + rq * 516 + kh * 256;

    float4 acc = make_float4(0.f, 0.f, 0.f, 0.f);

    #pragma unroll 4
    for (int k = 0; k < 256; k += 4) {
        float4 xv = *(const float4*)(xr + k);
        int kg = (kh * 256 + k) * 4 + cg;
        float4 w0 = w4[kg + 0];
        float4 w1 = w4[kg + 4];
        float4 w2 = w4[kg + 8];
        float4 w3 = w4[kg + 12];
        acc.x += xv.x * w0.x + xv.y * w1.x + xv.z * w2.x + xv.w * w3.x;
        acc.y += xv.x * w0.y + xv.y * w1.y + xv.z * w2.y + xv.w * w3.y;
        acc.z += xv.x * w0.z + xv.y * w1.z + xv.z * w2.z + xv.w * w3.z;
        acc.w += xv.x * w0.w + xv.y * w1.w + xv.z * w2.w + xv.w * w3.w;
    }

    acc.x += __shfl_xor(acc.x, 1);
    acc.y += __shfl_xor(acc.y, 1);
    acc.z += __shfl_xor(acc.z, 1);
    acc.w += __shfl_xor(acc.w, 1);

    if (kh == 0)
        *(float4*)(h + (size_t)(rbase + rq) * 16 + cg * 4) = acc;
}

// ---------------------------------------------------------------------------
// Binning (unchanged, proven): bucket = dst>>7, packed = src | (dst&127)<<17
// ---------------------------------------------------------------------------
__global__ __launch_bounds__(256) void bin_count_kernel(
    const int* __restrict__ ei, int* __restrict__ bucket_cnt)
{
    __shared__ int hist[NB];
    const int t = threadIdx.x;
    for (int i = t; i < NB; i += 256) hist[i] = 0;
    __syncthreads();
    const int stride = gridDim.x * 256;
    for (int e = blockIdx.x * 256 + t; e < N_EDGES; e += stride)
        atomicAdd(&hist[ei[N_EDGES + e] >> BSHIFT], 1);
    __syncthreads();
    for (int i = t; i < NB; i += 256)
        if (hist[i]) atomicAdd(&bucket_cnt[i], hist[i]);
}

__global__ __launch_bounds__(1024) void bucket_scan_kernel(
    const int* __restrict__ bucket_cnt, int* __restrict__ bucket_base,
    int* __restrict__ bucket_cursor)
{
    __shared__ int s[1024];
    const int t = threadIdx.x;
    s[t] = (t < NB) ? bucket_cnt[t] : 0;
    __syncthreads();
    for (int off = 1; off < 1024; off <<= 1) {
        int v = (t >= off) ? s[t - off] : 0;
        __syncthreads();
        s[t] += v;
        __syncthreads();
    }
    if (t < NB) {
        int excl = (t == 0) ? 0 : s[t - 1];
        bucket_base[t]   = excl;
        bucket_cursor[t] = excl;
        if (t == NB - 1) bucket_base[NB] = s[t];
    }
}

__global__ __launch_bounds__(256) void bin_place_kernel(
    const int* __restrict__ ei, int* __restrict__ bucket_cursor,
    int* __restrict__ packed)
{
    __shared__ int cnt[NB];
    __shared__ int base_off[NB];
    __shared__ int cur[NB];
    const int t = threadIdx.x;
    const int chunk = (N_EDGES + PLACE_BLOCKS - 1) / PLACE_BLOCKS;   // 8000
    const int cs = blockIdx.x * chunk;
    const int ce = min(cs + chunk, N_EDGES);

    for (int i = t; i < NB; i += 256) { cnt[i] = 0; cur[i] = 0; }
    __syncthreads();
    for (int e = cs + t; e < ce; e += 256)
        atomicAdd(&cnt[ei[N_EDGES + e] >> BSHIFT], 1);
    __syncthreads();
    for (int i = t; i < NB; i += 256)
        base_off[i] = cnt[i] ? atomicAdd(&bucket_cursor[i], cnt[i]) : 0;
    __syncthreads();
    for (int e = cs + t; e < ce; e += 256) {
        int s = ei[e];
        int d = ei[N_EDGES + e];
        int b = d >> BSHIFT;
        int pos = base_off[b] + atomicAdd(&cur[b], 1);
        packed[pos] = s | ((d & (BNODES - 1)) << 17);
    }
}

// ---------------------------------------------------------------------------
// csr_sort: one block per bucket. Counting sort by dst_local -> full
// dst-sorted csr_src + row_ptr. Each block writes ONLY its own contiguous
// ~16KB window -> lines stay dirty in its L2 until written back once.
// ---------------------------------------------------------------------------
__global__ __launch_bounds__(256) void csr_sort_kernel(
    const int* __restrict__ bucket_base, const int* __restrict__ packed,
    int* __restrict__ csr_src, int* __restrict__ row_ptr)
{
    __shared__ int hist[BNODES];
    __shared__ int excl[BNODES];
    __shared__ int cur[BNODES];
    __shared__ int scan[BNODES];
    const int t = threadIdx.x;
    const int b = blockIdx.x;
    if (t < BNODES) { hist[t] = 0; cur[t] = 0; }
    __syncthreads();

    const int bs = bucket_base[b];
    const int be = bucket_base[b + 1];
    for (int e = bs + t; e < be; e += 256)
        atomicAdd(&hist[packed[e] >> 17], 1);
    __syncthreads();

    if (t < BNODES) scan[t] = hist[t];
    __syncthreads();
    for (int off = 1; off < BNODES; off <<= 1) {
        int v = (t < BNODES && t >= off) ? scan[t - off] : 0;
        __syncthreads();
        if (t < BNODES) scan[t] += v;
        __syncthreads();
    }
    if (t < BNODES) {
        int ex = (t == 0) ? 0 : scan[t - 1];
        excl[t] = ex;
        int g = b * BNODES + t;
        if (g < N_NODES) row_ptr[g] = bs + ex;
    }
    if (b == NB - 1 && t == 0) row_ptr[N_NODES] = N_EDGES;
    __syncthreads();

    for (int e = bs + t; e < be; e += 256) {
        int p  = packed[e];
        int dl = p >> 17;
        int pos = bs + excl[dl] + atomicAdd(&cur[dl], 1);
        csr_src[pos] = p & 0x1FFFF;
    }
}

// ---------------------------------------------------------------------------
// gather1: wave per node, 64 lanes = 4 edge slots x 16 channels.
// Main loop 16 edges/iter -> 8 independent loads in flight per wave.
// Epilogue fuses +b1 / relu.
// ---------------------------------------------------------------------------
__global__ __launch_bounds__(256) void gather1_kernel(
    const int* __restrict__ row_ptr, const int* __restrict__ csr_src,
    const float* __restrict__ h, const float* __restrict__ b1,
    float* __restrict__ h1)
{
    const int node = (blockIdx.x * 256 + threadIdx.x) >> 6;
    if (node >= N_NODES) return;
    const int lane = threadIdx.x & 63;
    const int c = lane & 15, slot = lane >> 4;
    const int start = row_ptr[node], end = row_ptr[node + 1];

    float acc = 0.f;
    int e = start;
    for (; e + 16 <= end; e += 16) {
        int s0 = csr_src[e + slot * 4 + 0];
        int s1 = csr_src[e + slot * 4 + 1];
        int s2 = csr_src[e + slot * 4 + 2];
        int s3 = csr_src[e + slot * 4 + 3];
        float v0 = h[s0 * 16 + c];
        float v1 = h[s1 * 16 + c];
        float v2 = h[s2 * 16 + c];
        float v3 = h[s3 * 16 + c];
        acc += (v0 + v1) + (v2 + v3);
    }
    for (; e + 4 <= end; e += 4)
        acc += h[csr_src[e + slot] * 16 + c];
    if (e + slot < end)
        acc += h[csr_src[e + slot] * 16 + c];

    acc += __shfl_xor(acc, 16);
    acc += __shfl_xor(acc, 32);
    if (lane < 16)
        h1[(size_t)node * 16 + c] = fmaxf(acc + b1[c], 0.f);
}

// ---------------------------------------------------------------------------
// gather2 + gemm2 + bias + log_softmax, fully in-wave (shuffle-based).
// lane j<40 accumulates z_j = b2[j] + sum_k agg[k]*W2[k][j]; softmax via
// butterfly shuffles; writes out[node*40 + j].
// ---------------------------------------------------------------------------
__global__ __launch_bounds__(256) void gather2_kernel(
    const int* __restrict__ row_ptr, const int* __restrict__ csr_src,
    const float* __restrict__ h1, const float* __restrict__ W2,
    const float* __restrict__ b2, float* __restrict__ out)
{
    const int node = (blockIdx.x * 256 + threadIdx.x) >> 6;
    if (node >= N_NODES) return;
    const int lane = threadIdx.x & 63;
    const int c = lane & 15, slot = lane >> 4;

    // stage W2 column `lane` + b2[lane] in registers (coalesced, L1-hot)
    float w2c[16];
    float b2v = 0.f;
    if (lane < 40) {
        b2v = b2[lane];
        #pragma unroll
        for (int k = 0; k < 16; ++k) w2c[k] = W2[k * 40 + lane];
    } else {
        #pragma unroll
        for (int k = 0; k < 16; ++k) w2c[k] = 0.f;
    }

    const int start = row_ptr[node], end = row_ptr[node + 1];
    float acc = 0.f;
    int e = start;
    for (; e + 16 <= end; e += 16) {
        int s0 = csr_src[e + slot * 4 + 0];
        int s1 = csr_src[e + slot * 4 + 1];
        int s2 = csr_src[e + slot * 4 + 2];
        int s3 = csr_src[e + slot * 4 + 3];
        float v0 = h1[s0 * 16 + c];
        float v1 = h1[s1 * 16 + c];
        float v2 = h1[s2 * 16 + c];
        float v3 = h1[s3 * 16 + c];
        acc += (v0 + v1) + (v2 + v3);
    }
    for (; e + 4 <= end; e += 4)
        acc += h1[csr_src[e + slot] * 16 + c];
    if (e + slot < end)
        acc += h1[csr_src[e + slot] * 16 + c];

    acc += __shfl_xor(acc, 16);
    acc += __shfl_xor(acc, 32);
    // now lane k (any slot) holds channel (k&15) aggregate

    float z = b2v;
    #pragma unroll
    for (int k = 0; k < 16; ++k)
        z += __shfl(acc, k) * w2c[k];

    float zm = (lane < 40) ? z : -1e30f;
    #pragma unroll
    for (int off = 1; off < 64; off <<= 1)
        zm = fmaxf(zm, __shfl_xor(zm, off));
    float ex = (lane < 40) ? __expf(z - zm) : 0.f;
    float sum = ex;
    #pragma unroll
    for (int off = 1; off < 64; off <<= 1)
        sum += __shfl_xor(sum, off);
    const float lse = zm + __logf(sum);

    if (lane < 40)
        out[(size_t)node * 40 + lane] = z - lse;
}

// ---------------------------------------------------------------------------
extern "C" void kernel_launch(void* const* d_in, const int* in_sizes, int n_in,
                              void* d_out, int out_size, void* d_ws, size_t ws_size,
                              hipStream_t stream)
{
    const float* x  = (const float*)d_in[0];
    const int*   ei = (const int*)d_in[1];
    const float* W1 = (const float*)d_in[2];
    const float* b1 = (const float*)d_in[3];
    const float* W2 = (const float*)d_in[4];
    const float* b2 = (const float*)d_in[5];
    float* out = (float*)d_out;

    // ws (~32.4 MB): h (6.4MB) | csr (12.8MB) | packed (12.8MB, h1 overlays
    // its first 6.4MB after csr_sort) | rowp | bcnt | bbase | bcur
    float* h      = (float*)d_ws;
    int*   csr    = (int*)(h + (size_t)N_NODES * 16);
    int*   packed = csr + N_EDGES;
    float* h1     = (float*)packed;            // packed dead after csr_sort
    int*   rowp   = packed + N_EDGES;
    int*   bcnt   = rowp + (N_NODES + 1);
    int*   bbase  = bcnt + NB;
    int*   bcur   = bbase + (NB + 1);

    const int gemm1_blocks  = N_NODES / 32;                 // 3125 (exact)
    const int gather_blocks = (N_NODES + 3) / 4;            // 25000

    hipMemsetAsync(bcnt, 0, NB * sizeof(int), stream);
    bin_count_kernel  <<<256, 256, 0, stream>>>(ei, bcnt);
    bucket_scan_kernel<<<1, 1024, 0, stream>>>(bcnt, bbase, bcur);
    bin_place_kernel  <<<PLACE_BLOCKS, 256, 0, stream>>>(ei, bcur, packed);
    csr_sort_kernel   <<<NB, 256, 0, stream>>>(bbase, packed, csr, rowp);

    gemm1_kernel<<<gemm1_blocks, 256, 0, stream>>>(x, W1, h);

    gather1_kernel<<<gather_blocks, 256, 0, stream>>>(rowp, csr, h, b1, h1);
    gather2_kernel<<<gather_blocks, 256, 0, stream>>>(rowp, csr, h1, W2, b2, out);
}

// Round 5
// 545.312 us; speedup vs baseline: 1.2605x; 1.2605x over previous
//
#include <hip/hip_runtime.h>
#include <math.h>

#define N_NODES 100000
#define N_EDGES 3200000
#define BSHIFT 7
#define BNODES 128                         // nodes per bucket
#define NB 782                             // ceil(N_NODES/128)
#define PLACE_BLOCKS 400
#define G1_S 68                            // gemm1 LDS k-line stride (floats)

typedef float vfloat4 __attribute__((ext_vector_type(4)));  // clang-native
                                                            // (nontemporal ok)

// ---------------------------------------------------------------------------
// gemm1: h[N,16] = x[N,512] @ W1[512,16]
// R5b: R1's compute structure (thread=(rq,cg), 4 rows/thread, k-major LDS),
// with the four R1 defects fixed (R5 retry: nontemporal builtin needs a
// clang vector type, not HIP float4):
//  (1) x staged via __builtin_nontemporal_load -> x stops evicting W1 from
//      L1 (W1 = 32KB = L1 size). Theory: inner-loop W loads were L2-latency
//      misses in ALL prior variants (universal ~85% stall, VALUBusy 8-10%
//      at 16%/47%/53%/21% occupancy) because streamed x thrashed L1.
//  (2) 64-row, 64-thread (1-wave) blocks, 1563 blocks -> all ~6 waves/CU
//      resident, no 2:1 CU tail (R1's 391 blocks = 2 serial rounds).
//  (3) register prefetch of next k-chunk issued BEFORE compute, and NO
//      __syncthreads (single wave = wave-synchronous LDS; a barrier would
//      drain vmcnt and kill the overlap) -> staging latency hidden.
//  (4) XOR row-swizzle (row ^ ((k>>2)&7)<<3, stride 68): staging writes and
//      compute reads both exactly 2-way (free, m136); R1's stride-260 had
//      4.8M conflict cycles.
// ---------------------------------------------------------------------------
__global__ __launch_bounds__(64) void gemm1_kernel(
    const float* __restrict__ x, const float* __restrict__ W1,
    float* __restrict__ h, int nrows)
{
    __shared__ __align__(16) float xs[32 * G1_S];      // 8704 B
    const int t = threadIdx.x;
    const int rbase = blockIdx.x * 64;

    const int kl4  = (t & 7) * 4;          // this thread's k-offset (stage)
    const int rstg = t >> 3;               // staging row 0..7 (+8i)
    const int swz  = (t & 7) << 3;         // = (((kl4+j)>>2)&7)<<3, j<4

    const int rq = t >> 2;                 // 0..15 -> rows rq*4..rq*4+3
    const int cg = t & 3;                  // col group
    const float4* __restrict__ w4 = (const float4*)W1; // w4[k*4+cg]

    float4 acc0 = make_float4(0.f, 0.f, 0.f, 0.f);
    float4 acc1 = acc0, acc2 = acc0, acc3 = acc0;

    // prefetch chunk 0 into registers (nontemporal: keep W1 in L1)
    vfloat4 pre[8];
    #pragma unroll
    for (int i = 0; i < 8; ++i) {
        int rg = rbase + rstg + i * 8;
        pre[i] = (rg < nrows)
            ? __builtin_nontemporal_load(
                  (const vfloat4*)(x + (size_t)rg * 512 + kl4))
            : (vfloat4){0.f, 0.f, 0.f, 0.f};
    }

    for (int kc = 0; kc < 512; kc += 32) {
        // LDS write of staged chunk (k-major, swizzled rows): 2-way max
        #pragma unroll
        for (int i = 0; i < 8; ++i) {
            int row = (rstg + i * 8) ^ swz;
            float* p = xs + kl4 * G1_S + row;
            p[0 * G1_S] = pre[i].x;
            p[1 * G1_S] = pre[i].y;
            p[2 * G1_S] = pre[i].z;
            p[3 * G1_S] = pre[i].w;
        }
        // issue next chunk's loads now; they stay in flight under compute
        if (kc + 32 < 512) {
            #pragma unroll
            for (int i = 0; i < 8; ++i) {
                int rg = rbase + rstg + i * 8;
                pre[i] = (rg < nrows)
                    ? __builtin_nontemporal_load(
                          (const vfloat4*)(x + (size_t)rg * 512 + kc + 32 + kl4))
                    : (vfloat4){0.f, 0.f, 0.f, 0.f};
            }
        }

        // single wave: LDS ordering via lgkmcnt (no barrier -> no vmcnt drain)
        #pragma unroll
        for (int k4 = 0; k4 < 8; ++k4) {
            const int k0 = k4 * 4;
            const int rr = (rq * 4) ^ (k4 << 3);   // swizzled read row base
            float4 xv0 = *(const float4*)(xs + (k0 + 0) * G1_S + rr);
            float4 xv1 = *(const float4*)(xs + (k0 + 1) * G1_S + rr);
            float4 xv2 = *(const float4*)(xs + (k0 + 2) * G1_S + rr);
            float4 xv3 = *(const float4*)(xs + (k0 + 3) * G1_S + rr);
            float4 wv0 = w4[(kc + k0 + 0) * 4 + cg];
            float4 wv1 = w4[(kc + k0 + 1) * 4 + cg];
            float4 wv2 = w4[(kc + k0 + 2) * 4 + cg];
            float4 wv3 = w4[(kc + k0 + 3) * 4 + cg];

            #define GCN_UPD(xv, wv)                                           \
                acc0.x += (xv).x * (wv).x; acc0.y += (xv).x * (wv).y;         \
                acc0.z += (xv).x * (wv).z; acc0.w += (xv).x * (wv).w;         \
                acc1.x += (xv).y * (wv).x; acc1.y += (xv).y * (wv).y;         \
                acc1.z += (xv).y * (wv).z; acc1.w += (xv).y * (wv).w;         \
                acc2.x += (xv).z * (wv).x; acc2.y += (xv).z * (wv).y;         \
                acc2.z += (xv).z * (wv).z; acc2.w += (xv).z * (wv).w;         \
                acc3.x += (xv).w * (wv).x; acc3.y += (xv).w * (wv).y;         \
                acc3.z += (xv).w * (wv).z; acc3.w += (xv).w * (wv).w;
            GCN_UPD(xv0, wv0)
            GCN_UPD(xv1, wv1)
            GCN_UPD(xv2, wv2)
            GCN_UPD(xv3, wv3)
            #undef GCN_UPD
        }
    }

    {
        int rg = rbase + rq * 4;
        if (rg + 0 < nrows) *(float4*)(h + (size_t)(rg + 0) * 16 + cg * 4) = acc0;
        if (rg + 1 < nrows) *(float4*)(h + (size_t)(rg + 1) * 16 + cg * 4) = acc1;
        if (rg + 2 < nrows) *(float4*)(h + (size_t)(rg + 2) * 16 + cg * 4) = acc2;
        if (rg + 3 < nrows) *(float4*)(h + (size_t)(rg + 3) * 16 + cg * 4) = acc3;
    }
}

// ---------------------------------------------------------------------------
// Binning (unchanged, proven): bucket = dst>>7, packed = src | (dst&127)<<17
// ---------------------------------------------------------------------------
__global__ __launch_bounds__(256) void bin_count_kernel(
    const int* __restrict__ ei, int* __restrict__ bucket_cnt)
{
    __shared__ int hist[NB];
    const int t = threadIdx.x;
    for (int i = t; i < NB; i += 256) hist[i] = 0;
    __syncthreads();
    const int stride = gridDim.x * 256;
    for (int e = blockIdx.x * 256 + t; e < N_EDGES; e += stride)
        atomicAdd(&hist[ei[N_EDGES + e] >> BSHIFT], 1);
    __syncthreads();
    for (int i = t; i < NB; i += 256)
        if (hist[i]) atomicAdd(&bucket_cnt[i], hist[i]);
}

__global__ __launch_bounds__(1024) void bucket_scan_kernel(
    const int* __restrict__ bucket_cnt, int* __restrict__ bucket_base,
    int* __restrict__ bucket_cursor)
{
    __shared__ int s[1024];
    const int t = threadIdx.x;
    s[t] = (t < NB) ? bucket_cnt[t] : 0;
    __syncthreads();
    for (int off = 1; off < 1024; off <<= 1) {
        int v = (t >= off) ? s[t - off] : 0;
        __syncthreads();
        s[t] += v;
        __syncthreads();
    }
    if (t < NB) {
        int excl = (t == 0) ? 0 : s[t - 1];
        bucket_base[t]   = excl;
        bucket_cursor[t] = excl;
        if (t == NB - 1) bucket_base[NB] = s[t];
    }
}

__global__ __launch_bounds__(256) void bin_place_kernel(
    const int* __restrict__ ei, int* __restrict__ bucket_cursor,
    int* __restrict__ packed)
{
    __shared__ int cnt[NB];
    __shared__ int base_off[NB];
    __shared__ int cur[NB];
    const int t = threadIdx.x;
    const int chunk = (N_EDGES + PLACE_BLOCKS - 1) / PLACE_BLOCKS;   // 8000
    const int cs = blockIdx.x * chunk;
    const int ce = min(cs + chunk, N_EDGES);

    for (int i = t; i < NB; i += 256) { cnt[i] = 0; cur[i] = 0; }
    __syncthreads();
    for (int e = cs + t; e < ce; e += 256)
        atomicAdd(&cnt[ei[N_EDGES + e] >> BSHIFT], 1);
    __syncthreads();
    for (int i = t; i < NB; i += 256)
        base_off[i] = cnt[i] ? atomicAdd(&bucket_cursor[i], cnt[i]) : 0;
    __syncthreads();
    for (int e = cs + t; e < ce; e += 256) {
        int s = ei[e];
        int d = ei[N_EDGES + e];
        int b = d >> BSHIFT;
        int pos = base_off[b] + atomicAdd(&cur[b], 1);
        packed[pos] = s | ((d & (BNODES - 1)) << 17);
    }
}

// ---------------------------------------------------------------------------
// csr_sort: one block per bucket. Counting sort by dst_local -> full
// dst-sorted csr_src + row_ptr. Each block writes ONLY its own contiguous
// ~16KB window -> lines stay dirty in its L2 until written back once.
// ---------------------------------------------------------------------------
__global__ __launch_bounds__(256) void csr_sort_kernel(
    const int* __restrict__ bucket_base, const int* __restrict__ packed,
    int* __restrict__ csr_src, int* __restrict__ row_ptr)
{
    __shared__ int hist[BNODES];
    __shared__ int excl[BNODES];
    __shared__ int cur[BNODES];
    __shared__ int scan[BNODES];
    const int t = threadIdx.x;
    const int b = blockIdx.x;
    if (t < BNODES) { hist[t] = 0; cur[t] = 0; }
    __syncthreads();

    const int bs = bucket_base[b];
    const int be = bucket_base[b + 1];
    for (int e = bs + t; e < be; e += 256)
        atomicAdd(&hist[packed[e] >> 17], 1);
    __syncthreads();

    if (t < BNODES) scan[t] = hist[t];
    __syncthreads();
    for (int off = 1; off < BNODES; off <<= 1) {
        int v = (t < BNODES && t >= off) ? scan[t - off] : 0;
        __syncthreads();
        if (t < BNODES) scan[t] += v;
        __syncthreads();
    }
    if (t < BNODES) {
        int ex = (t == 0) ? 0 : scan[t - 1];
        excl[t] = ex;
        int g = b * BNODES + t;
        if (g < N_NODES) row_ptr[g] = bs + ex;
    }
    if (b == NB - 1 && t == 0) row_ptr[N_NODES] = N_EDGES;
    __syncthreads();

    for (int e = bs + t; e < be; e += 256) {
        int p  = packed[e];
        int dl = p >> 17;
        int pos = bs + excl[dl] + atomicAdd(&cur[dl], 1);
        csr_src[pos] = p & 0x1FFFF;
    }
}

// ---------------------------------------------------------------------------
// gather1: wave per node, 64 lanes = 4 edge slots x 16 channels.
// Main loop 16 edges/iter -> 8 independent loads in flight per wave.
// Epilogue fuses +b1 / relu.
// ---------------------------------------------------------------------------
__global__ __launch_bounds__(256) void gather1_kernel(
    const int* __restrict__ row_ptr, const int* __restrict__ csr_src,
    const float* __restrict__ h, const float* __restrict__ b1,
    float* __restrict__ h1)
{
    const int node = (blockIdx.x * 256 + threadIdx.x) >> 6;
    if (node >= N_NODES) return;
    const int lane = threadIdx.x & 63;
    const int c = lane & 15, slot = lane >> 4;
    const int start = row_ptr[node], end = row_ptr[node + 1];

    float acc = 0.f;
    int e = start;
    for (; e + 16 <= end; e += 16) {
        int s0 = csr_src[e + slot * 4 + 0];
        int s1 = csr_src[e + slot * 4 + 1];
        int s2 = csr_src[e + slot * 4 + 2];
        int s3 = csr_src[e + slot * 4 + 3];
        float v0 = h[s0 * 16 + c];
        float v1 = h[s1 * 16 + c];
        float v2 = h[s2 * 16 + c];
        float v3 = h[s3 * 16 + c];
        acc += (v0 + v1) + (v2 + v3);
    }
    for (; e + 4 <= end; e += 4)
        acc += h[csr_src[e + slot] * 16 + c];
    if (e + slot < end)
        acc += h[csr_src[e + slot] * 16 + c];

    acc += __shfl_xor(acc, 16);
    acc += __shfl_xor(acc, 32);
    if (lane < 16)
        h1[(size_t)node * 16 + c] = fmaxf(acc + b1[c], 0.f);
}

// ---------------------------------------------------------------------------
// gather2 + gemm2 + bias + log_softmax, fully in-wave (shuffle-based).
// lane j<40 accumulates z_j = b2[j] + sum_k agg[k]*W2[k][j]; softmax via
// butterfly shuffles; writes out[node*40 + j].
// ---------------------------------------------------------------------------
__global__ __launch_bounds__(256) void gather2_kernel(
    const int* __restrict__ row_ptr, const int* __restrict__ csr_src,
    const float* __restrict__ h1, const float* __restrict__ W2,
    const float* __restrict__ b2, float* __restrict__ out)
{
    const int node = (blockIdx.x * 256 + threadIdx.x) >> 6;
    if (node >= N_NODES) return;
    const int lane = threadIdx.x & 63;
    const int c = lane & 15, slot = lane >> 4;

    // stage W2 column `lane` + b2[lane] in registers (coalesced, L1-hot)
    float w2c[16];
    float b2v = 0.f;
    if (lane < 40) {
        b2v = b2[lane];
        #pragma unroll
        for (int k = 0; k < 16; ++k) w2c[k] = W2[k * 40 + lane];
    } else {
        #pragma unroll
        for (int k = 0; k < 16; ++k) w2c[k] = 0.f;
    }

    const int start = row_ptr[node], end = row_ptr[node + 1];
    float acc = 0.f;
    int e = start;
    for (; e + 16 <= end; e += 16) {
        int s0 = csr_src[e + slot * 4 + 0];
        int s1 = csr_src[e + slot * 4 + 1];
        int s2 = csr_src[e + slot * 4 + 2];
        int s3 = csr_src[e + slot * 4 + 3];
        float v0 = h1[s0 * 16 + c];
        float v1 = h1[s1 * 16 + c];
        float v2 = h1[s2 * 16 + c];
        float v3 = h1[s3 * 16 + c];
        acc += (v0 + v1) + (v2 + v3);
    }
    for (; e + 4 <= end; e += 4)
        acc += h1[csr_src[e + slot] * 16 + c];
    if (e + slot < end)
        acc += h1[csr_src[e + slot] * 16 + c];

    acc += __shfl_xor(acc, 16);
    acc += __shfl_xor(acc, 32);
    // now lane k (any slot) holds channel (k&15) aggregate

    float z = b2v;
    #pragma unroll
    for (int k = 0; k < 16; ++k)
        z += __shfl(acc, k) * w2c[k];

    float zm = (lane < 40) ? z : -1e30f;
    #pragma unroll
    for (int off = 1; off < 64; off <<= 1)
        zm = fmaxf(zm, __shfl_xor(zm, off));
    float ex = (lane < 40) ? __expf(z - zm) : 0.f;
    float sum = ex;
    #pragma unroll
    for (int off = 1; off < 64; off <<= 1)
        sum += __shfl_xor(sum, off);
    const float lse = zm + __logf(sum);

    if (lane < 40)
        out[(size_t)node * 40 + lane] = z - lse;
}

// ---------------------------------------------------------------------------
extern "C" void kernel_launch(void* const* d_in, const int* in_sizes, int n_in,
                              void* d_out, int out_size, void* d_ws, size_t ws_size,
                              hipStream_t stream)
{
    const float* x  = (const float*)d_in[0];
    const int*   ei = (const int*)d_in[1];
    const float* W1 = (const float*)d_in[2];
    const float* b1 = (const float*)d_in[3];
    const float* W2 = (const float*)d_in[4];
    const float* b2 = (const float*)d_in[5];
    float* out = (float*)d_out;

    // ws (~32.4 MB): h (6.4MB) | csr (12.8MB) | packed (12.8MB, h1 overlays
    // its first 6.4MB after csr_sort) | rowp | bcnt | bbase | bcur
    float* h      = (float*)d_ws;
    int*   csr    = (int*)(h + (size_t)N_NODES * 16);
    int*   packed = csr + N_EDGES;
    float* h1     = (float*)packed;            // packed dead after csr_sort
    int*   rowp   = packed + N_EDGES;
    int*   bcnt   = rowp + (N_NODES + 1);
    int*   bbase  = bcnt + NB;
    int*   bcur   = bbase + (NB + 1);

    const int gemm1_blocks  = (N_NODES + 63) / 64;          // 1563
    const int gather_blocks = (N_NODES + 3) / 4;            // 25000

    hipMemsetAsync(bcnt, 0, NB * sizeof(int), stream);
    bin_count_kernel  <<<256, 256, 0, stream>>>(ei, bcnt);
    bucket_scan_kernel<<<1, 1024, 0, stream>>>(bcnt, bbase, bcur);
    bin_place_kernel  <<<PLACE_BLOCKS, 256, 0, stream>>>(ei, bcur, packed);
    csr_sort_kernel   <<<NB, 256, 0, stream>>>(bbase, packed, csr, rowp);

    gemm1_kernel<<<gemm1_blocks, 64, 0, stream>>>(x, W1, h, N_NODES);

    gather1_kernel<<<gather_blocks, 256, 0, stream>>>(rowp, csr, h, b1, h1);
    gather2_kernel<<<gather_blocks, 256, 0, stream>>>(rowp, csr, h1, W2, b2, out);
}